// Round 5
// baseline (259.985 us; speedup 1.0000x reference)
//
#include <hip/hip_runtime.h>
#include <hip/hip_fp16.h>
#include <hip/hip_cooperative_groups.h>

namespace cg = cooperative_groups;

namespace {

constexpr int kB  = 16;
constexpr int kF  = 4096;   // T_FEAT
constexpr int kD  = 512;
constexpr int kTT = 1024;   // T_TOK
constexpr int kC  = 64;     // 64-row chunks along F
constexpr int kD2 = kD / 2; // 256 float2 lanes per row
constexpr int kD4 = kD / 4; // 128 float4 lanes per row
constexpr int kBlocks = kB * kC;               // 1024
constexpr int kTokPerBlk = (kB * kTT) / kBlocks; // 16

__device__ inline void acc4(float4& a, const float4& v) {
    a.x += v.x; a.y += v.y; a.z += v.z; a.w += v.w;
}
__device__ inline float4 unpack_h4(const ushort4& u) {
    return make_float4(__half2float(__ushort_as_half(u.x)),
                       __half2float(__ushort_as_half(u.y)),
                       __half2float(__ushort_as_half(u.z)),
                       __half2float(__ushort_as_half(u.w)));
}

__device__ inline float4 prefix_at(const ushort4* __restrict__ Pc4,
                                   const float4* __restrict__ O644,
                                   int b, int r, int q) {
    float4 acc = O644[((size_t)(b * kC + (r >> 6))) * kD4 + q];
    acc4(acc, unpack_h4(Pc4[((size_t)(b * kF + r)) * kD4 + q]));
    return acc;
}

// ======================= fused cooperative kernel =======================
__global__ __launch_bounds__(256, 4) void fused_k(
    const float2* __restrict__ feats,   // [B][F][kD2]
    const int*    __restrict__ flens,
    const int*    __restrict__ tlens,
    const float2* __restrict__ aligns,  // [B*TT]
    __half2*      __restrict__ Pc,      // [B][F][kD2] chunk-local fp16 prefix
    float2*       __restrict__ S,       // [B][kC][kD2] chunk totals
    float2*       __restrict__ O64,     // [B][kC][kD2] exclusive chunk offsets
    float4*       __restrict__ out,     // [B*TT][kD4]
    float*        __restrict__ out_lens)
{
    cg::grid_group grid = cg::this_grid();
    const int bid = blockIdx.x;
    const int tid = threadIdx.x;

    // ---- Phase 1: per-(b,c) chunk: fp16 chunk-local prefix + f32 chunk sum
    {
        int b = bid >> 6, c = bid & 63;
        int flen = flens[b];
        int base = c * 64;
        float2 r = make_float2(0.f, 0.f);
        int nval = flen - base;
        if (nval > 64) nval = 64;
        if (nval > 0) {
            const float2* p = feats + ((size_t)(b * kF + base)) * kD2 + tid;
            __half2* o = Pc + ((size_t)(b * kF + base)) * kD2 + tid;
            int i = 0;
            for (; i + 8 <= nval; i += 8) {
#pragma unroll
                for (int j = 0; j < 8; ++j) {
                    float2 v = p[(size_t)(i + j) * kD2];
                    r.x += v.x; r.y += v.y;
                    o[(size_t)(i + j) * kD2] = __floats2half2_rn(r.x, r.y);
                }
            }
            for (; i < nval; ++i) {
                float2 v = p[(size_t)i * kD2];
                r.x += v.x; r.y += v.y;
                o[(size_t)i * kD2] = __floats2half2_rn(r.x, r.y);
            }
        }
        S[((size_t)bid) * kD2 + tid] = r;
    }

    grid.sync();

    // ---- Phase 2: exclusive scan of chunk totals (16 blocks, float2 lanes)
    if (bid < (kB * kD2) / 256) {          // 16 blocks
        int gid = bid * 256 + tid;         // 0..4095
        int d2 = gid & (kD2 - 1);
        int b  = gid >> 8;
        float2 r = make_float2(0.f, 0.f);
#pragma unroll 8
        for (int c = 0; c < kC; ++c) {
            size_t idx = ((size_t)(b * kC + c)) * kD2 + d2;
            O64[idx] = r;
            float2 v = S[idx];
            r.x += v.x; r.y += v.y;
        }
    }

    grid.sync();

    // ---- Phase 3: gather, 16 tokens per block (2 at a time)
    {
        const ushort4* Pc4  = (const ushort4*)Pc;
        const float4*  O644 = (const float4*)O64;
        int q = tid & 127;
        int which = tid >> 7;
        int tok0 = bid * kTokPerBlk;
        for (int k = 0; k < kTokPerBlk; k += 2) {
            int blk = tok0 + k + which;
            int t = blk & (kTT - 1);
            int b = blk >> 10;
            int tlen = tlens[b];
            int flen = flens[b];
            float fl = (float)flen;
            float2 a = aligns[blk];
            int s = (int)(a.x * fl);
            int e = (int)(a.y * fl);
            if (e > kF - 1) e = kF - 1;
            int cnt = e - s + 1;
            float4 res = make_float4(0.f, 0.f, 0.f, 0.f);
            if (t < tlen && cnt > 0 && s < kF) {
                int er = e;     if (er > flen - 1) er = flen - 1;
                float4 hi = prefix_at(Pc4, O644, b, er, q);
                float4 lo = make_float4(0.f, 0.f, 0.f, 0.f);
                if (s > 0) {
                    int sr = s - 1; if (sr > flen - 1) sr = flen - 1;
                    lo = prefix_at(Pc4, O644, b, sr, q);
                }
                float fc = (float)cnt;
                res = make_float4((hi.x - lo.x) / fc, (hi.y - lo.y) / fc,
                                  (hi.z - lo.z) / fc, (hi.w - lo.w) / fc);
            }
            out[((size_t)blk) * kD4 + q] = res;
            if (t == 0 && q == 0 && which == 0) out_lens[b] = (float)tlen;
        }
    }
}

// ======================= non-cooperative fallback path =======================
__global__ void chunk_prefix_k(const float2* __restrict__ feats,
                               const int* __restrict__ flens,
                               __half2* __restrict__ Pc,
                               float2* __restrict__ S) {
    int bid = blockIdx.x;
    int tid = threadIdx.x;
    int b = bid >> 6, c = bid & 63;
    int flen = flens[b];
    int base = c * 64;
    float2 r = make_float2(0.f, 0.f);
    int nval = flen - base;
    if (nval > 64) nval = 64;
    if (nval > 0) {
        const float2* p = feats + ((size_t)(b * kF + base)) * kD2 + tid;
        __half2* o = Pc + ((size_t)(b * kF + base)) * kD2 + tid;
        for (int i = 0; i < nval; ++i) {
            float2 v = p[(size_t)i * kD2];
            r.x += v.x; r.y += v.y;
            o[(size_t)i * kD2] = __floats2half2_rn(r.x, r.y);
        }
    }
    S[((size_t)bid) * kD2 + tid] = r;
}

__global__ void chunk_offsets_k(const float2* __restrict__ S,
                                float2* __restrict__ O64) {
    int gid = blockIdx.x * blockDim.x + threadIdx.x;  // kB*kD2 = 4096
    int d2 = gid & (kD2 - 1);
    int b  = gid >> 8;
    float2 r = make_float2(0.f, 0.f);
    for (int c = 0; c < kC; ++c) {
        size_t idx = ((size_t)(b * kC + c)) * kD2 + d2;
        O64[idx] = r;
        float2 v = S[idx];
        r.x += v.x; r.y += v.y;
    }
}

__global__ void gather_k(const ushort4* __restrict__ Pc4,
                         const float4* __restrict__ O644,
                         const int* __restrict__ flens,
                         const int* __restrict__ tlens,
                         const float2* __restrict__ aligns,
                         float4* __restrict__ out,
                         float* __restrict__ out_lens) {
    int blk = blockIdx.x;
    int t = blk & (kTT - 1);
    int b = blk >> 10;
    int q = threadIdx.x;
    int tlen = tlens[b];
    int flen = flens[b];
    float fl = (float)flen;
    float2 a = aligns[blk];
    int s = (int)(a.x * fl);
    int e = (int)(a.y * fl);
    if (e > kF - 1) e = kF - 1;
    int cnt = e - s + 1;
    float4 res = make_float4(0.f, 0.f, 0.f, 0.f);
    if (t < tlen && cnt > 0 && s < kF) {
        int er = e;     if (er > flen - 1) er = flen - 1;
        float4 hi = prefix_at(Pc4, O644, b, er, q);
        float4 lo = make_float4(0.f, 0.f, 0.f, 0.f);
        if (s > 0) {
            int sr = s - 1; if (sr > flen - 1) sr = flen - 1;
            lo = prefix_at(Pc4, O644, b, sr, q);
        }
        float fc = (float)cnt;
        res = make_float4((hi.x - lo.x) / fc, (hi.y - lo.y) / fc,
                          (hi.z - lo.z) / fc, (hi.w - lo.w) / fc);
    }
    out[((size_t)blk) * kD4 + q] = res;
    if (t == 0 && q == 0) out_lens[b] = (float)tlen;
}

__global__ void direct_k(const float4* __restrict__ feats,
                         const int* __restrict__ flens,
                         const int* __restrict__ tlens,
                         const float2* __restrict__ aligns,
                         float4* __restrict__ out,
                         float* __restrict__ out_lens) {
    int blk = blockIdx.x;
    int t = blk & (kTT - 1);
    int b = blk >> 10;
    int q = threadIdx.x;
    int tlen = tlens[b];
    float fl = (float)flens[b];
    float2 a = aligns[blk];
    int s = (int)(a.x * fl);
    int e = (int)(a.y * fl);
    if (e > kF - 1) e = kF - 1;
    int cnt = e - s + 1;
    float4 res = make_float4(0.f, 0.f, 0.f, 0.f);
    if (t < tlen && cnt > 0 && s < kF) {
        const float4* p = feats + ((size_t)(b * kF + s)) * kD4 + q;
        float4 r = make_float4(0.f, 0.f, 0.f, 0.f);
        for (int i = 0; i < cnt; ++i) acc4(r, p[(size_t)i * kD4]);
        float fc = (float)cnt;
        res = make_float4(r.x / fc, r.y / fc, r.z / fc, r.w / fc);
    }
    out[((size_t)blk) * kD4 + q] = res;
    if (t == 0 && q == 0) out_lens[b] = (float)tlen;
}

} // namespace

extern "C" void kernel_launch(void* const* d_in, const int* in_sizes, int n_in,
                              void* d_out, int out_size, void* d_ws, size_t ws_size,
                              hipStream_t stream) {
    const float2* feats2 = (const float2*)d_in[0];            // [B, F, D] f32
    const int*    flens  = (const int*)d_in[1];               // [B]
    // d_in[2]: asr_token_ids (int64) -- unused
    const int*    tlens  = (const int*)d_in[3];               // [B]
    const float2* aligns = (const float2*)d_in[4];            // [B, TT, 2] f32

    float* out      = (float*)d_out;                          // [B, TT, D] then [B] lengths
    float* out_lens = out + (size_t)kB * kTT * kD;

    const size_t needPc  = (size_t)kB * kF * kD * sizeof(unsigned short); // 64 MiB
    const size_t needS   = (size_t)kB * kC * kD * sizeof(float);          // 2 MiB
    const size_t needO64 = needS;                                         // 2 MiB

    if (ws_size >= needPc + needS + needO64) {
        __half2* Pc  = (__half2*)d_ws;
        float2*  S   = (float2*)((char*)d_ws + needPc);
        float2*  O64 = (float2*)((char*)d_ws + needPc + needS);
        float4*  out4 = (float4*)out;

        void* args[] = { (void*)&feats2, (void*)&flens, (void*)&tlens, (void*)&aligns,
                         (void*)&Pc, (void*)&S, (void*)&O64, (void*)&out4, (void*)&out_lens };
        hipError_t err = hipLaunchCooperativeKernel((const void*)fused_k,
                                                    dim3(kBlocks), dim3(256),
                                                    args, 0, stream);
        if (err != hipSuccess) {
            // fallback: proven 3-kernel path
            chunk_prefix_k<<<kBlocks, 256, 0, stream>>>(feats2, flens, Pc, S);
            chunk_offsets_k<<<(kB * kD2) / 256, 256, 0, stream>>>(S, O64);
            gather_k<<<kB * kTT, kD4, 0, stream>>>((const ushort4*)Pc, (const float4*)O64,
                                                   flens, tlens, aligns,
                                                   (float4*)out, out_lens);
        }
    } else {
        direct_k<<<kB * kTT, kD4, 0, stream>>>((const float4*)feats2, flens, tlens, aligns,
                                               (float4*)out, out_lens);
    }
}

// Round 6
// 67.690 us; speedup vs baseline: 3.8408x; 3.8408x over previous
//
#include <hip/hip_runtime.h>
#include <hip/hip_fp16.h>

namespace {

constexpr int kB  = 16;
constexpr int kF  = 4096;   // T_FEAT
constexpr int kD  = 512;
constexpr int kTT = 1024;   // T_TOK
constexpr int kSC = 32;     // sub-chunk rows
constexpr int kNC = kF / kSC; // 128 sub-chunks
constexpr int kD4 = kD / 4; // 128 float4 lanes per row

__device__ inline void acc4(float4& a, const float4& v) {
    a.x += v.x; a.y += v.y; a.z += v.z; a.w += v.w;
}
__device__ inline ushort4 pack_h4(const float4& v) {
    ushort4 u;
    u.x = __half_as_ushort(__float2half_rn(v.x));
    u.y = __half_as_ushort(__float2half_rn(v.y));
    u.z = __half_as_ushort(__float2half_rn(v.z));
    u.w = __half_as_ushort(__float2half_rn(v.w));
    return u;
}
__device__ inline float4 unpack_h4(const ushort4& u) {
    return make_float4(__half2float(__ushort_as_half(u.x)),
                       __half2float(__ushort_as_half(u.y)),
                       __half2float(__ushort_as_half(u.z)),
                       __half2float(__ushort_as_half(u.w)));
}

// ---------------- K1: per-sub-chunk fp16 chunk-local inclusive prefix
// Pc[b][r][d] (fp16) = sum of rows [c*32 .. r], c = r/32, valid rows only.
// 262144 threads = 1024 blocks (4/CU).
__global__ __launch_bounds__(256) void chunk_prefix_k(
    const float4* __restrict__ feats,
    const int* __restrict__ flens,
    ushort4* __restrict__ Pc) {
    int tid = blockIdx.x * blockDim.x + threadIdx.x;
    int q = tid & (kD4 - 1);
    int c = (tid >> 7) & (kNC - 1);
    int b = tid >> 14;
    int flen = flens[b];
    int base = c * kSC;
    int nval = flen - base;
    if (nval <= 0) return;
    if (nval > kSC) nval = kSC;
    size_t fbase = ((size_t)(b * kF + base)) * kD4 + q;
    const float4* p = feats + fbase;
    ushort4* o = Pc + fbase;
    float4 r = make_float4(0.f, 0.f, 0.f, 0.f);
    if (nval == kSC) {
#pragma unroll 8
        for (int i = 0; i < kSC; ++i) {
            acc4(r, p[(size_t)i * kD4]);
            o[(size_t)i * kD4] = pack_h4(r);
        }
    } else {
        for (int i = 0; i < nval; ++i) {
            acc4(r, p[(size_t)i * kD4]);
            o[(size_t)i * kD4] = pack_h4(r);
        }
    }
}

// ---------------- K2: exclusive scan of sub-chunk totals -> O (f32)
// Sub-chunk totals read from Pc at each sub-chunk's last valid row.
__global__ __launch_bounds__(256) void chunk_offsets_k(
    const unsigned short* __restrict__ PcH,
    const int* __restrict__ flens,
    float* __restrict__ O) {
    int gid = blockIdx.x * blockDim.x + threadIdx.x;  // kB*kD = 8192
    int d = gid & (kD - 1);
    int b = gid >> 9;
    int flen = flens[b];
    float r = 0.f;
#pragma unroll 8
    for (int c = 0; c < kNC; ++c) {
        O[((size_t)(b * kNC + c)) * kD + d] = r;
        int start = c * kSC;
        if (start < flen) {
            int last = start + kSC - 1;
            if (last > flen - 1) last = flen - 1;
            r += __half2float(__ushort_as_half(PcH[((size_t)(b * kF + last)) * kD + d]));
        }
    }
}

// ---------------- K3: per-token gather, 2 tokens per 256-thread block
__global__ __launch_bounds__(256) void gather_k(
    const ushort4* __restrict__ Pc4,
    const float4* __restrict__ O4,
    const int* __restrict__ flens,
    const int* __restrict__ tlens,
    const float2* __restrict__ aligns,
    float4* __restrict__ out,
    float* __restrict__ out_lens) {
    int q = threadIdx.x & 127;
    int which = threadIdx.x >> 7;
    int blk = blockIdx.x * 2 + which;    // b*kTT + t
    int t = blk & (kTT - 1);
    int b = blk >> 10;
    int tlen = tlens[b];
    int flen = flens[b];
    float fl = (float)flen;
    float2 a = aligns[blk];
    int s = (int)(a.x * fl);             // trunc toward zero == .astype(int32)
    int e = (int)(a.y * fl);
    if (e > kF - 1) e = kF - 1;
    int cnt = e - s + 1;
    float4 res = make_float4(0.f, 0.f, 0.f, 0.f);
    if (t < tlen && cnt > 0 && s < kF) {
        int er = e;      if (er > flen - 1) er = flen - 1;
        int sr = s - 1;  if (sr > flen - 1) sr = flen - 1;
        bool haveLo = (s > 0);
        // issue all loads up front (ILP)
        float4  oHi = O4[((size_t)(b * kNC + (er >> 5))) * kD4 + q];
        ushort4 pHi = Pc4[((size_t)(b * kF + er)) * kD4 + q];
        float4  oLo = make_float4(0.f, 0.f, 0.f, 0.f);
        ushort4 pLo = make_ushort4(0, 0, 0, 0);
        if (haveLo) {
            oLo = O4[((size_t)(b * kNC + (sr >> 5))) * kD4 + q];
            pLo = Pc4[((size_t)(b * kF + sr)) * kD4 + q];
        }
        float4 hi = unpack_h4(pHi); acc4(hi, oHi);
        float4 lo = make_float4(0.f, 0.f, 0.f, 0.f);
        if (haveLo) { lo = unpack_h4(pLo); acc4(lo, oLo); }
        float fc = (float)cnt;
        res = make_float4((hi.x - lo.x) / fc, (hi.y - lo.y) / fc,
                          (hi.z - lo.z) / fc, (hi.w - lo.w) / fc);
    }
    out[((size_t)blk) * kD4 + q] = res;
    if (t == 0 && q == 0) out_lens[b] = (float)tlen;
}

// ---------------- Fallback: direct summation (if ws too small) ----------------
__global__ void direct_k(const float4* __restrict__ feats,
                         const int* __restrict__ flens,
                         const int* __restrict__ tlens,
                         const float2* __restrict__ aligns,
                         float4* __restrict__ out,
                         float* __restrict__ out_lens) {
    int blk = blockIdx.x;
    int t = blk & (kTT - 1);
    int b = blk >> 10;
    int q = threadIdx.x;
    int tlen = tlens[b];
    float fl = (float)flens[b];
    float2 a = aligns[blk];
    int s = (int)(a.x * fl);
    int e = (int)(a.y * fl);
    if (e > kF - 1) e = kF - 1;
    int cnt = e - s + 1;
    float4 res = make_float4(0.f, 0.f, 0.f, 0.f);
    if (t < tlen && cnt > 0 && s < kF) {
        const float4* p = feats + ((size_t)(b * kF + s)) * kD4 + q;
        float4 r = make_float4(0.f, 0.f, 0.f, 0.f);
        for (int i = 0; i < cnt; ++i) acc4(r, p[(size_t)i * kD4]);
        float fc = (float)cnt;
        res = make_float4(r.x / fc, r.y / fc, r.z / fc, r.w / fc);
    }
    out[((size_t)blk) * kD4 + q] = res;
    if (t == 0 && q == 0) out_lens[b] = (float)tlen;
}

} // namespace

extern "C" void kernel_launch(void* const* d_in, const int* in_sizes, int n_in,
                              void* d_out, int out_size, void* d_ws, size_t ws_size,
                              hipStream_t stream) {
    const float4* feats  = (const float4*)d_in[0];            // [B, F, D] f32
    const int*    flens  = (const int*)d_in[1];               // [B]
    // d_in[2]: asr_token_ids (int64) -- unused
    const int*    tlens  = (const int*)d_in[3];               // [B]
    const float2* aligns = (const float2*)d_in[4];            // [B, TT, 2] f32

    float* out      = (float*)d_out;                          // [B, TT, D] then [B] lengths
    float* out_lens = out + (size_t)kB * kTT * kD;

    const size_t needPc = (size_t)kB * kF * kD * sizeof(unsigned short); // 64 MiB
    const size_t needO  = (size_t)kB * kNC * kD * sizeof(float);         // 4 MiB

    if (ws_size >= needPc + needO) {
        ushort4* Pc = (ushort4*)d_ws;
        float*   O  = (float*)((char*)d_ws + needPc);

        int n1 = kB * kNC * kD4;                               // 262144
        chunk_prefix_k<<<n1 / 256, 256, 0, stream>>>(feats, flens, Pc);
        chunk_offsets_k<<<(kB * kD) / 256, 256, 0, stream>>>(
            (const unsigned short*)Pc, flens, O);
        gather_k<<<(kB * kTT) / 2, 256, 0, stream>>>(
            Pc, (const float4*)O, flens, tlens, aligns, (float4*)out, out_lens);
    } else {
        direct_k<<<kB * kTT, kD4, 0, stream>>>(feats, flens, tlens, aligns,
                                               (float4*)out, out_lens);
    }
}